// Round 9
// baseline (142.309 us; speedup 1.0000x reference)
//
#include <hip/hip_runtime.h>

#define HW 28
#define NPIX 784
#define NB 512
#define PADW2 34                 // row stride in float2 (cols -3..30)
#define PADH 35                  // rows -3..31 (row 34 = safe pad for odd half)
#define IMG_F2 (PADH * PADW2)    // 1190 float2 = 9520 B per buffer

typedef float v2f __attribute__((ext_vector_type(2)));

// ---------------------------------------------------------------------------
// di-split 7x2 conv: lane pair (2k, 2k+1) shares one 7-row x 2-col tile.
// half=0 owns kernel rows di 0..3; half=1 owns di 4..6 (+ zero row di=7).
// Uniform code: r = k - dloc independent of half. Each half reads only its
// 10 tap rows. Partials combined via shfl_xor(1). Live set ~114 VGPR, under
// the measured hard 128-VGPR cap (r8: cap holds even at 2 waves/EU).
// W = (qw, ew) = (w*e^{aw}, e^{aw}); out = sum((ev,pv).(qw,ew)) / sum(ev*ew)
// ---------------------------------------------------------------------------
__device__ __forceinline__ void conv_di(const float2* buf,
                                        const float2* wbase,  // [4][8] float2
                                        int R0, int j2, int half,
                                        float o0[7], float o1[7])
{
    v2f W[4][7];
    {
        const float4* wp = (const float4*)wbase;
#pragma unroll
        for (int dl = 0; dl < 4; ++dl) {
            float4 qa = wp[dl * 4 + 0], qb = wp[dl * 4 + 1];
            float4 qc = wp[dl * 4 + 2], qd = wp[dl * 4 + 3];
            W[dl][0] = (v2f){qa.x, qa.y}; W[dl][1] = (v2f){qa.z, qa.w};
            W[dl][2] = (v2f){qb.x, qb.y}; W[dl][3] = (v2f){qb.z, qb.w};
            W[dl][4] = (v2f){qc.x, qc.y}; W[dl][5] = (v2f){qc.z, qc.w};
            W[dl][6] = (v2f){qd.x, qd.y};                     // qd.zw = pad
        }
    }

    v2f   sN0[7], sN1[7];
    float sD0[7], sD1[7];
#pragma unroll
    for (int r = 0; r < 7; ++r) {
        sN0[r] = (v2f){0.f, 0.f}; sN1[r] = (v2f){0.f, 0.f};
        sD0[r] = 0.f; sD1[r] = 0.f;
    }

    const int rowbase = R0 + (half << 2);
#pragma unroll
    for (int k = 0; k < 10; ++k) {
        const float4* rq = (const float4*)(buf + (rowbase + k) * PADW2 + j2);
        float4 q0 = rq[0], q1 = rq[1], q2 = rq[2], q3 = rq[3];
        v2f tp[8] = {{q0.x, q0.y}, {q0.z, q0.w}, {q1.x, q1.y}, {q1.z, q1.w},
                     {q2.x, q2.y}, {q2.z, q2.w}, {q3.x, q3.y}, {q3.z, q3.w}};
#pragma unroll
        for (int dl = 0; dl < 4; ++dl) {
            const int r = k - dl;
            if (r < 0 || r > 6) continue;           // compile-time fold
#pragma unroll
            for (int t = 0; t < 7; ++t) {
                v2f wq = W[dl][t];
                sN0[r] = __builtin_elementwise_fma(tp[t],     wq, sN0[r]);
                sN1[r] = __builtin_elementwise_fma(tp[t + 1], wq, sN1[r]);
                sD0[r] = fmaf(tp[t][0],     wq[1], sD0[r]);
                sD1[r] = fmaf(tp[t + 1][0], wq[1], sD1[r]);
            }
        }
    }

#pragma unroll
    for (int r = 0; r < 7; ++r) {
        float n0 = sN0[r][0] + sN0[r][1];
        float n1 = sN1[r][0] + sN1[r][1];
        float d0 = sD0[r], d1 = sD1[r];
        n0 += __shfl_xor(n0, 1); d0 += __shfl_xor(d0, 1);
        n1 += __shfl_xor(n1, 1); d1 += __shfl_xor(d1, 1);
        o0[r] = n0 * __builtin_amdgcn_rcpf(d0);
        o1[r] = n1 * __builtin_amdgcn_rcpf(d1);
    }
}

// ---------------------------------------------------------------------------
// Fused smorph x2 + 4x4 mean pool. 128 threads (2 waves) per image; tile =
// lane-pair (di-split). LDS ~20 KB -> 8 blocks/CU. 3 barriers.
// ---------------------------------------------------------------------------
__global__ __launch_bounds__(128, 2) void smorph_fused_kernel(
    const float* __restrict__ x,       // [512,784]
    const float* __restrict__ sw,      // [8,2,49]
    const float* __restrict__ sa,      // [8,2]
    float* __restrict__ feat)          // [512,392]
{
    __shared__ __align__(16) float2 buf1[IMG_F2];
    __shared__ __align__(16) float2 buf2[IMG_F2];
    __shared__ __align__(16) float2 wpk[2][2][4][8];  // [stage][half][dloc][t pad8]

    const int bx  = blockIdx.x;        // 4096 = 8 f x 512 b
    const int f   = bx >> 9;
    const int b   = bx & 511;
    const int tid = threadIdx.x;

    const float a1 = sa[f * 2 + 0];
    const float a2 = sa[f * 2 + 1];

    // Per-block weight table fill: exactly 128 entries = 128 threads.
    {
        int s  = tid >> 6;
        int h  = (tid >> 5) & 1;
        int dl = (tid >> 3) & 3;
        int t  = tid & 7;
        int di = h * 4 + dl;
        float2 val = make_float2(0.f, 0.f);
        if (di < 7 && t < 7) {
            float a = sa[f * 2 + s];
            float w = sw[(f * 2 + s) * 49 + di * 7 + t];
            float e = __expf(a * w);
            val = make_float2(w * e, e);
        }
        wpk[s][h][dl][t] = val;
    }

    // Phase 0: buf1 = padded (ev,pv); borders of BOTH buffers = (1,0).
    const float* src = x + (size_t)b * NPIX;
    for (int idx = tid; idx < IMG_F2; idx += 128) {
        int pi = idx / PADW2;
        int pj = idx - pi * PADW2;
        if (pi >= 3 && pi < 31 && pj >= 3 && pj < 31) {
            float v = src[(pi - 3) * HW + (pj - 3)];
            float e = __expf(a1 * v);
            buf1[idx] = make_float2(e, v * e);
        } else {
            buf1[idx] = make_float2(1.f, 0.f);
            buf2[idx] = make_float2(1.f, 0.f);
        }
    }
    __syncthreads();

    const bool act  = (tid < 112);
    const int tile  = tid >> 1;        // 0..55
    const int half  = tid & 1;
    const int s     = tile / 14;       // strip (rows 7s..7s+6)
    const int c     = tile - s * 14;   // col pair
    const int R0    = 7 * s;
    const int j2    = 2 * c;

    float o0[7], o1[7];
    if (act) {
        conv_di(buf1, &wpk[0][half][0][0], R0, j2, half, o0, o1);
        // stage-2 (ev,pv) into buf2 interior; half0 writes col j2, half1 j2+1
        const int col = j2 + 3 + half;
#pragma unroll
        for (int r = 0; r < 7; ++r) {
            float o = half ? o1[r] : o0[r];
            float e = __expf(a2 * o);
            buf2[(R0 + r + 3) * PADW2 + col] = make_float2(e, o * e);
        }
    }
    __syncthreads();

    float* outp = (float*)buf1;        // conv1 reads complete; safe to alias
    if (act) {
        conv_di(buf2, &wpk[1][half][0][0], R0, j2, half, o0, o1);
#pragma unroll
        for (int r = 0; r < 7; ++r)
            outp[(R0 + r) * HW + j2 + half] = half ? o1[r] : o0[r];
    }
    __syncthreads();

    // 4x4 mean pool -> feat[b, f*49 + t]
    if (tid < 49) {
        int pi = tid / 7;
        int pj = tid - pi * 7;
        float sum = 0.f;
#pragma unroll
        for (int di = 0; di < 4; ++di)
#pragma unroll
            for (int dj = 0; dj < 4; ++dj)
                sum += outp[(pi * 4 + di) * HW + (pj * 4 + dj)];
        feat[(size_t)b * 392 + f * 49 + tid] = sum * 0.0625f;
    }
}

// ---------------------------------------------------------------------------
// MLP 392->120->84->10, sigmoid. 32 blocks x 16 batch rows. Register tiling:
// thread = (neuron, row-octet); each weight float4 amortized over 32 FMA.
// LDS activations; per-k LDS reads are 2-address broadcasts (conflict-free).
// ---------------------------------------------------------------------------
__device__ __forceinline__ float sigmoidf_(float s) {
    return __builtin_amdgcn_rcpf(1.f + __expf(-s));
}

__global__ __launch_bounds__(256) void mlp_kernel(
    const float* __restrict__ feat,  // [512,392]
    const float* __restrict__ W1, const float* __restrict__ b1,
    const float* __restrict__ W2, const float* __restrict__ b2,
    const float* __restrict__ W3, const float* __restrict__ b3,
    float* __restrict__ out)         // [512,10]
{
    __shared__ __align__(16) float fsh[16 * 392];
    __shared__ __align__(16) float h1[16 * 120];
    __shared__ __align__(16) float h2[16 * 84];
    const int r0  = blockIdx.x * 16;
    const int tid = threadIdx.x;

    {
        const float4* fsrc = (const float4*)(feat + (size_t)r0 * 392);
        float4* fdst = (float4*)fsh;
        for (int q = tid; q < 16 * 98; q += 256) fdst[q] = fsrc[q];
    }
    __syncthreads();

    // L1: 120 neurons x 2 row-octets = 240 threads
    if (tid < 240) {
        int n  = tid >> 1;
        int rh = tid & 1;
        const float4* wr = (const float4*)(W1 + n * 392);
        const float4* fv = (const float4*)fsh;
        float acc[8] = {0.f, 0.f, 0.f, 0.f, 0.f, 0.f, 0.f, 0.f};
        for (int k = 0; k < 98; ++k) {
            float4 w = wr[k];
#pragma unroll
            for (int j = 0; j < 8; ++j) {
                float4 v = fv[(rh * 8 + j) * 98 + k];
                acc[j] = fmaf(w.x, v.x, fmaf(w.y, v.y, fmaf(w.z, v.z, fmaf(w.w, v.w, acc[j]))));
            }
        }
        float bb = b1[n];
#pragma unroll
        for (int j = 0; j < 8; ++j)
            h1[(rh * 8 + j) * 120 + n] = sigmoidf_(acc[j] + bb);
    }
    __syncthreads();

    // L2: 84 neurons x 2 row-octets = 168 threads
    if (tid < 168) {
        int n  = tid >> 1;
        int rh = tid & 1;
        const float4* wr = (const float4*)(W2 + n * 120);
        const float4* hv = (const float4*)h1;
        float acc[8] = {0.f, 0.f, 0.f, 0.f, 0.f, 0.f, 0.f, 0.f};
        for (int k = 0; k < 30; ++k) {
            float4 w = wr[k];
#pragma unroll
            for (int j = 0; j < 8; ++j) {
                float4 v = hv[(rh * 8 + j) * 30 + k];
                acc[j] = fmaf(w.x, v.x, fmaf(w.y, v.y, fmaf(w.z, v.z, fmaf(w.w, v.w, acc[j]))));
            }
        }
        float bb = b2[n];
#pragma unroll
        for (int j = 0; j < 8; ++j)
            h2[(rh * 8 + j) * 84 + n] = sigmoidf_(acc[j] + bb);
    }
    __syncthreads();

    // L3: 10 neurons x 16 rows = 160 threads
    if (tid < 160) {
        int row = tid / 10;
        int n   = tid - row * 10;
        const float4* wr = (const float4*)(W3 + n * 84);
        const float4* hv = (const float4*)(h2 + row * 84);
        float c0 = 0.f, c1 = 0.f, c2 = 0.f, c3 = 0.f;
#pragma unroll
        for (int k = 0; k < 21; ++k) {
            float4 w = wr[k];
            float4 v = hv[k];
            c0 = fmaf(w.x, v.x, c0);
            c1 = fmaf(w.y, v.y, c1);
            c2 = fmaf(w.z, v.z, c2);
            c3 = fmaf(w.w, v.w, c3);
        }
        out[(size_t)(r0 + row) * 10 + n] = sigmoidf_((c0 + c1) + (c2 + c3) + b3[n]);
    }
}

extern "C" void kernel_launch(void* const* d_in, const int* in_sizes, int n_in,
                              void* d_out, int out_size, void* d_ws, size_t ws_size,
                              hipStream_t stream) {
    const float* x  = (const float*)d_in[0];
    const float* sw = (const float*)d_in[1];
    const float* sa = (const float*)d_in[2];
    const float* W1 = (const float*)d_in[3];
    const float* b1 = (const float*)d_in[4];
    const float* W2 = (const float*)d_in[5];
    const float* b2 = (const float*)d_in[6];
    const float* W3 = (const float*)d_in[7];
    const float* b3 = (const float*)d_in[8];
    float* out = (float*)d_out;

    float* feat = (float*)d_ws;                    // 512*392 floats

    smorph_fused_kernel<<<4096, 128, 0, stream>>>(x, sw, sa, feat);
    mlp_kernel<<<32, 256, 0, stream>>>(feat, W1, b1, W2, b2, W3, b3, out);
}

// Round 10
// 137.491 us; speedup vs baseline: 1.0350x; 1.0350x over previous
//
#include <hip/hip_runtime.h>

#define HW 28
#define NPIX 784
#define NB 512
#define PADW2 34                 // row stride in float2 (cols -3..30)
#define PADH 34                  // rows -3..30
#define IMG_F2 (PADH * PADW2)    // 1156 float2 = 9248 B

typedef float v2f __attribute__((ext_vector_type(2)));

// ---------------------------------------------------------------------------
// 7x2 output tile per thread. Per row: 4 ds_read_b128 (8 float2 taps).
// W[49] preloaded from LDS; compiler remats part of it in-loop at the 128-
// VGPR cap (r5-r9 data) — the fix is occupancy (4 waves/SIMD), not residency.
// W = (qw, ew) = (w*e^{aw}, e^{aw}); out = sum((ev,pv).(qw,ew)) / sum(ev*ew)
// ---------------------------------------------------------------------------
__device__ __forceinline__ void conv2col(const float2* sbuf,
                                         const float2* wlds,   // LDS, 16B-aligned
                                         int R0, int c, float o0[7], float o1[7])
{
    v2f W[49];
    {
        const float4* wp = (const float4*)wlds;    // broadcast, conflict-free
#pragma unroll
        for (int k = 0; k < 24; ++k) {
            float4 q = wp[k];
            W[2 * k]     = (v2f){q.x, q.y};
            W[2 * k + 1] = (v2f){q.z, q.w};
        }
        float2 lastw = wlds[48];
        W[48] = (v2f){lastw.x, lastw.y};
    }

    v2f   sN0[7], sN1[7];
    float sD0[7], sD1[7];
#pragma unroll
    for (int r = 0; r < 7; ++r) {
        sN0[r] = (v2f){0.f, 0.f}; sN1[r] = (v2f){0.f, 0.f};
        sD0[r] = 0.f; sD1[r] = 0.f;
    }
#pragma unroll
    for (int rr = 0; rr < 13; ++rr) {
        const float4* rq = (const float4*)(sbuf + (R0 + rr) * PADW2 + 2 * c);
        float4 q0 = rq[0], q1 = rq[1], q2 = rq[2], q3 = rq[3];
        v2f tp[8] = {{q0.x, q0.y}, {q0.z, q0.w}, {q1.x, q1.y}, {q1.z, q1.w},
                     {q2.x, q2.y}, {q2.z, q2.w}, {q3.x, q3.y}, {q3.z, q3.w}};
#pragma unroll
        for (int r = 0; r < 7; ++r) {
            if (r > rr || rr - r > 6) continue;     // compile-time fold
            const int di = rr - r;
#pragma unroll
            for (int t = 0; t < 7; ++t) {
                v2f wq = W[di * 7 + t];             // (qw, ew)
                sN0[r] = __builtin_elementwise_fma(tp[t],     wq, sN0[r]);
                sN1[r] = __builtin_elementwise_fma(tp[t + 1], wq, sN1[r]);
                sD0[r] = fmaf(tp[t][0],     wq[1], sD0[r]);
                sD1[r] = fmaf(tp[t + 1][0], wq[1], sD1[r]);
            }
        }
    }
#pragma unroll
    for (int r = 0; r < 7; ++r) {
        o0[r] = (sN0[r][0] + sN0[r][1]) * __builtin_amdgcn_rcpf(sD0[r]);
        o1[r] = (sN1[r][0] + sN1[r][1]) * __builtin_amdgcn_rcpf(sD1[r]);
    }
}

// ---------------------------------------------------------------------------
// Fused smorph x2 + 4x4 mean pool. ONE WAVE PER IMAGE, 64-thread blocks,
// ZERO barriers, SINGLE in-place evpv buffer (stage-2 (ev,pv) overwrites the
// interior after conv1 — safe by wave program order; borders stay (1,0)).
// LDS ~10.1 KB/block -> 16 blocks/CU = 4 waves/SIMD (the max the measured
// 128-VGPR cap allows) — doubles r8's wave parallelism to hide lgkm waits.
// ---------------------------------------------------------------------------
__global__ __launch_bounds__(64) void smorph_fused_kernel(
    const float* __restrict__ x,       // [512,784]
    const float* __restrict__ sw,      // [8,2,49]
    const float* __restrict__ sa,      // [8,2]
    float* __restrict__ feat)          // [512,392]
{
    __shared__ __align__(16) float2 buf[IMG_F2];   // 9248 B
    __shared__ __align__(16) float2 wtab[2][52];   //  832 B (52 -> stage1 16B-aligned)

    const int bx   = blockIdx.x;       // 4096 = 8 f x 512 b
    const int f    = bx >> 9;
    const int b    = bx & 511;
    const int lane = threadIdx.x;      // 0..63

    const float a1 = sa[f * 2 + 0];
    const float a2 = sa[f * 2 + 1];

    // Weight tables: (qw, ew) for both stages (98 entries, 64 lanes, 2 passes)
#pragma unroll
    for (int q = 0; q < 2; ++q) {
        int idx = lane + q * 64;
        if (idx < 98) {
            int s = idx / 49;
            int t = idx - s * 49;
            float a = sa[f * 2 + s];
            float w = sw[(f * 2 + s) * 49 + t];
            float e = __expf(a * w);
            wtab[s][t] = make_float2(w * e, e);
        }
    }

    // Phase 0: buf = padded (ev,pv) of x; borders = (1,0) (SAME zero-pad)
    const float* src = x + (size_t)b * NPIX;
    for (int idx = lane; idx < IMG_F2; idx += 64) {
        int pi = idx / PADW2;
        int pj = idx - pi * PADW2;
        float2 val = make_float2(1.f, 0.f);
        if (pi >= 3 && pi < 31 && pj >= 3 && pj < 31) {
            float v = src[(pi - 3) * HW + (pj - 3)];
            float e = __expf(a1 * v);
            val = make_float2(e, v * e);
        }
        buf[idx] = val;
    }

    const bool act = (lane < 56);
    const int s  = lane / 14;          // strip (output rows 7s..7s+6)
    const int c  = lane - s * 14;      // column pair 0..13
    const int R0 = 7 * s;
    const int j2 = 2 * c;

    // Stage 1 conv (program order after phase 0; single wave => no barrier)
    float o0[7], o1[7];
    if (act) conv2col(buf, wtab[0], R0, c, o0, o1);

    // Stage-2 (ev,pv) overwrite interior in place (all conv1 reads are done)
    if (act) {
#pragma unroll
        for (int r = 0; r < 7; ++r) {
            float e0 = __expf(a2 * o0[r]);
            float e1 = __expf(a2 * o1[r]);
            buf[(R0 + r + 3) * PADW2 + (j2 + 3)] = make_float2(e0, o0[r] * e0);
            buf[(R0 + r + 3) * PADW2 + (j2 + 4)] = make_float2(e1, o1[r] * e1);
        }
    }

    // Stage 2 conv
    if (act) conv2col(buf, wtab[1], R0, c, o0, o1);

    // Dense 28x28 plane aliased over buf (all conv2 reads are done)
    float* outp = (float*)buf;
    if (act) {
#pragma unroll
        for (int r = 0; r < 7; ++r) {
            outp[(R0 + r) * HW + j2]     = o0[r];
            outp[(R0 + r) * HW + j2 + 1] = o1[r];
        }
    }

    // 4x4 mean pool -> feat[b, f*49 + t]
    if (lane < 49) {
        int pi = lane / 7;
        int pj = lane - pi * 7;
        float sum = 0.f;
#pragma unroll
        for (int di = 0; di < 4; ++di)
#pragma unroll
            for (int dj = 0; dj < 4; ++dj)
                sum += outp[(pi * 4 + di) * HW + (pj * 4 + dj)];
        feat[(size_t)b * 392 + f * 49 + lane] = sum * 0.0625f;
    }
}

// ---------------------------------------------------------------------------
// MLP 392->120->84->10, sigmoid. One block per batch row; dots split across
// lanes with component-parallel accumulators + shuffle reduce. (r2-r8 proven)
// ---------------------------------------------------------------------------
__device__ __forceinline__ float sigmoidf_(float s) {
    return __builtin_amdgcn_rcpf(1.f + __expf(-s));
}

__global__ __launch_bounds__(256) void mlp_kernel(
    const float* __restrict__ feat,
    const float* __restrict__ W1, const float* __restrict__ b1,
    const float* __restrict__ W2, const float* __restrict__ b2,
    const float* __restrict__ W3, const float* __restrict__ b3,
    float* __restrict__ out)
{
    __shared__ __align__(16) float fsh[392];
    __shared__ __align__(16) float h1[120];
    __shared__ __align__(16) float h2[84];
    const int b   = blockIdx.x;
    const int tid = threadIdx.x;

    if (tid < 98)
        ((float4*)fsh)[tid] = ((const float4*)(feat + (size_t)b * 392))[tid];
    __syncthreads();

    if (tid < 240) {
        int n = tid >> 1, h = tid & 1;
        const float4* wr = (const float4*)(W1 + n * 392);
        const float4* fv = (const float4*)fsh;
        float c0 = 0.f, c1 = 0.f, c2 = 0.f, c3 = 0.f;
#pragma unroll 7
        for (int k = h; k < 98; k += 2) {
            float4 w = wr[k];
            float4 v = fv[k];
            c0 = fmaf(w.x, v.x, c0);
            c1 = fmaf(w.y, v.y, c1);
            c2 = fmaf(w.z, v.z, c2);
            c3 = fmaf(w.w, v.w, c3);
        }
        float acc = (c0 + c1) + (c2 + c3);
        acc += __shfl_xor(acc, 1);
        if (h == 0) h1[n] = sigmoidf_(acc + b1[n]);
    }
    __syncthreads();

    if (tid < 168) {
        int n = tid >> 1, h = tid & 1;
        const float4* wr = (const float4*)(W2 + n * 120);
        const float4* hv = (const float4*)h1;
        float c0 = 0.f, c1 = 0.f, c2 = 0.f, c3 = 0.f;
#pragma unroll
        for (int k = h; k < 30; k += 2) {
            float4 w = wr[k];
            float4 v = hv[k];
            c0 = fmaf(w.x, v.x, c0);
            c1 = fmaf(w.y, v.y, c1);
            c2 = fmaf(w.z, v.z, c2);
            c3 = fmaf(w.w, v.w, c3);
        }
        float acc = (c0 + c1) + (c2 + c3);
        acc += __shfl_xor(acc, 1);
        if (h == 0) h2[n] = sigmoidf_(acc + b2[n]);
    }
    __syncthreads();

    if (tid < 40) {
        int n = tid >> 2, q = tid & 3;
        const float4* wr = (const float4*)(W3 + n * 84);
        const float4* hv = (const float4*)h2;
        float c0 = 0.f, c1 = 0.f, c2 = 0.f, c3 = 0.f;
        for (int k = q; k < 21; k += 4) {
            float4 w = wr[k];
            float4 v = hv[k];
            c0 = fmaf(w.x, v.x, c0);
            c1 = fmaf(w.y, v.y, c1);
            c2 = fmaf(w.z, v.z, c2);
            c3 = fmaf(w.w, v.w, c3);
        }
        float acc = (c0 + c1) + (c2 + c3);
        acc += __shfl_xor(acc, 1);
        acc += __shfl_xor(acc, 2);
        if (q == 0) out[(size_t)b * 10 + n] = sigmoidf_(acc + b3[n]);
    }
}

extern "C" void kernel_launch(void* const* d_in, const int* in_sizes, int n_in,
                              void* d_out, int out_size, void* d_ws, size_t ws_size,
                              hipStream_t stream) {
    const float* x  = (const float*)d_in[0];
    const float* sw = (const float*)d_in[1];
    const float* sa = (const float*)d_in[2];
    const float* W1 = (const float*)d_in[3];
    const float* b1 = (const float*)d_in[4];
    const float* W2 = (const float*)d_in[5];
    const float* b2 = (const float*)d_in[6];
    const float* W3 = (const float*)d_in[7];
    const float* b3 = (const float*)d_in[8];
    float* out = (float*)d_out;

    float* feat = (float*)d_ws;                    // 512*392 floats

    smorph_fused_kernel<<<4096, 64, 0, stream>>>(x, sw, sa, feat);
    mlp_kernel<<<NB, 256, 0, stream>>>(feat, W1, b1, W2, b2, W3, b3, out);
}

// Round 11
// 128.541 us; speedup vs baseline: 1.1071x; 1.0696x over previous
//
#include <hip/hip_runtime.h>

#define HW 28
#define NPIX 784
#define NB 512
#define PADW2 34                 // row stride in float2 (cols -3..30)
#define PADH 34                  // rows -3..30
#define IMG_F2 (PADH * PADW2)    // 1156 float2 = 9248 B

typedef float v2f __attribute__((ext_vector_type(2)));

// ---------------------------------------------------------------------------
// 7x2 output tile per thread. Per row: 4 ds_read_b128 (8 float2 taps).
// W = (qw, ew) = (w*e^{aw}, e^{aw}); out = sum((ev,pv).(qw,ew)) / sum(ev*ew)
// ---------------------------------------------------------------------------
__device__ __forceinline__ void conv2col(const float2* sbuf,
                                         const float2* wlds,   // LDS, 16B-aligned
                                         int R0, int c, float o0[7], float o1[7])
{
    v2f W[49];
    {
        const float4* wp = (const float4*)wlds;    // broadcast, conflict-free
#pragma unroll
        for (int k = 0; k < 24; ++k) {
            float4 q = wp[k];
            W[2 * k]     = (v2f){q.x, q.y};
            W[2 * k + 1] = (v2f){q.z, q.w};
        }
        float2 lastw = wlds[48];
        W[48] = (v2f){lastw.x, lastw.y};
    }

    v2f   sN0[7], sN1[7];
    float sD0[7], sD1[7];
#pragma unroll
    for (int r = 0; r < 7; ++r) {
        sN0[r] = (v2f){0.f, 0.f}; sN1[r] = (v2f){0.f, 0.f};
        sD0[r] = 0.f; sD1[r] = 0.f;
    }
#pragma unroll
    for (int rr = 0; rr < 13; ++rr) {
        const float4* rq = (const float4*)(sbuf + (R0 + rr) * PADW2 + 2 * c);
        float4 q0 = rq[0], q1 = rq[1], q2 = rq[2], q3 = rq[3];
        v2f tp[8] = {{q0.x, q0.y}, {q0.z, q0.w}, {q1.x, q1.y}, {q1.z, q1.w},
                     {q2.x, q2.y}, {q2.z, q2.w}, {q3.x, q3.y}, {q3.z, q3.w}};
#pragma unroll
        for (int r = 0; r < 7; ++r) {
            if (r > rr || rr - r > 6) continue;     // compile-time fold
            const int di = rr - r;
#pragma unroll
            for (int t = 0; t < 7; ++t) {
                v2f wq = W[di * 7 + t];             // (qw, ew)
                sN0[r] = __builtin_elementwise_fma(tp[t],     wq, sN0[r]);
                sN1[r] = __builtin_elementwise_fma(tp[t + 1], wq, sN1[r]);
                sD0[r] = fmaf(tp[t][0],     wq[1], sD0[r]);
                sD1[r] = fmaf(tp[t + 1][0], wq[1], sD1[r]);
            }
        }
    }
#pragma unroll
    for (int r = 0; r < 7; ++r) {
        o0[r] = (sN0[r][0] + sN0[r][1]) * __builtin_amdgcn_rcpf(sD0[r]);
        o1[r] = (sN1[r][0] + sN1[r][1]) * __builtin_amdgcn_rcpf(sD1[r]);
    }
}

__device__ __forceinline__ float sigmoidf_(float s) {
    return __builtin_amdgcn_rcpf(1.f + __expf(-s));
}

// ---------------------------------------------------------------------------
// FULLY FUSED: one block per image. 4 waves; wave w computes filter branches
// 2w and 2w+1 (each: smorph x2 + 4x4 pool) into an LDS feat row, then the
// block runs the 392->120->84->10 MLP inline. Branch convs are barrier-free
// (per-wave LDS ordering, r8/r10-proven); ONE barrier before the MLP.
// LDS 42.7 KB -> 3 blocks/CU. launch_bounds(256,4) pins VGPR <= 128.
// ---------------------------------------------------------------------------
__global__ __launch_bounds__(256, 4) void smorph_net_kernel(
    const float* __restrict__ x,       // [512,784]
    const float* __restrict__ sw,      // [8,2,49]
    const float* __restrict__ sa,      // [8,2]
    const float* __restrict__ W1, const float* __restrict__ b1,
    const float* __restrict__ W2, const float* __restrict__ b2,
    const float* __restrict__ W3, const float* __restrict__ b3,
    float* __restrict__ out)           // [512,10]
{
    __shared__ __align__(16) float2 bufs[4][IMG_F2];   // 36,992 B
    __shared__ __align__(16) float2 wtab[4][2][52];    //  3,328 B
    __shared__ __align__(16) float  feat[392];
    __shared__ __align__(16) float  h1[120];
    __shared__ __align__(16) float  h2[84];

    const int b    = blockIdx.x;       // 512 blocks
    const int tid  = threadIdx.x;
    const int wv   = tid >> 6;
    const int lane = tid & 63;

    float2* buf = bufs[wv];
    const float* src = x + (size_t)b * NPIX;

    const bool act = (lane < 56);
    const int s  = lane / 14;          // strip (output rows 7s..7s+6)
    const int c  = lane - s * 14;      // column pair 0..13
    const int R0 = 7 * s;
    const int j2 = 2 * c;

#pragma unroll
    for (int half = 0; half < 2; ++half) {
        const int f = wv * 2 + half;
        const float a1 = sa[f * 2 + 0];
        const float a2 = sa[f * 2 + 1];

        // weight tables for this branch (wave-local; program order protects)
        if (lane < 49) {
            float w1v = sw[(f * 2 + 0) * 49 + lane];
            float e1  = __expf(a1 * w1v);
            wtab[wv][0][lane] = make_float2(w1v * e1, e1);
            float w2v = sw[(f * 2 + 1) * 49 + lane];
            float e2  = __expf(a2 * w2v);
            wtab[wv][1][lane] = make_float2(w2v * e2, e2);
        }

        // phase 0: buf = padded (ev,pv); borders (1,0)  (SAME zero-pad)
        for (int idx = lane; idx < IMG_F2; idx += 64) {
            int pi = idx / PADW2;
            int pj = idx - pi * PADW2;
            float2 val = make_float2(1.f, 0.f);
            if (pi >= 3 && pi < 31 && pj >= 3 && pj < 31) {
                float v = src[(pi - 3) * HW + (pj - 3)];
                float e = __expf(a1 * v);
                val = make_float2(e, v * e);
            }
            buf[idx] = val;
        }

        float o0[7], o1[7];
        if (act) conv2col(buf, wtab[wv][0], R0, c, o0, o1);

        // stage-2 (ev,pv) overwrite interior in place (conv1 reads all issued)
        if (act) {
#pragma unroll
            for (int r = 0; r < 7; ++r) {
                float e0 = __expf(a2 * o0[r]);
                float e1 = __expf(a2 * o1[r]);
                buf[(R0 + r + 3) * PADW2 + (j2 + 3)] = make_float2(e0, o0[r] * e0);
                buf[(R0 + r + 3) * PADW2 + (j2 + 4)] = make_float2(e1, o1[r] * e1);
            }
        }

        if (act) conv2col(buf, wtab[wv][1], R0, c, o0, o1);

        // dense 28x28 plane aliased over buf (conv2 reads all issued)
        float* outp = (float*)buf;
        if (act) {
#pragma unroll
            for (int r = 0; r < 7; ++r) {
                outp[(R0 + r) * HW + j2]     = o0[r];
                outp[(R0 + r) * HW + j2 + 1] = o1[r];
            }
        }

        // 4x4 mean pool -> LDS feat[f*49 + t]
        if (lane < 49) {
            int pi = lane / 7;
            int pj = lane - pi * 7;
            float sum = 0.f;
#pragma unroll
            for (int di = 0; di < 4; ++di)
#pragma unroll
                for (int dj = 0; dj < 4; ++dj)
                    sum += outp[(pi * 4 + di) * HW + (pj * 4 + dj)];
            feat[f * 49 + lane] = sum * 0.0625f;
        }
    }
    __syncthreads();

    // ---- inline MLP on this image's feat row ----
    if (tid < 240) {
        int n = tid >> 1, h = tid & 1;
        const float4* wr = (const float4*)(W1 + n * 392);
        const float4* fv = (const float4*)feat;
        float c0 = 0.f, c1 = 0.f, c2 = 0.f, c3 = 0.f;
#pragma unroll 7
        for (int k = h; k < 98; k += 2) {
            float4 w = wr[k];
            float4 v = fv[k];
            c0 = fmaf(w.x, v.x, c0);
            c1 = fmaf(w.y, v.y, c1);
            c2 = fmaf(w.z, v.z, c2);
            c3 = fmaf(w.w, v.w, c3);
        }
        float acc = (c0 + c1) + (c2 + c3);
        acc += __shfl_xor(acc, 1);
        if (h == 0) h1[n] = sigmoidf_(acc + b1[n]);
    }
    __syncthreads();

    if (tid < 168) {
        int n = tid >> 1, h = tid & 1;
        const float4* wr = (const float4*)(W2 + n * 120);
        const float4* hv = (const float4*)h1;
        float c0 = 0.f, c1 = 0.f, c2 = 0.f, c3 = 0.f;
#pragma unroll
        for (int k = h; k < 30; k += 2) {
            float4 w = wr[k];
            float4 v = hv[k];
            c0 = fmaf(w.x, v.x, c0);
            c1 = fmaf(w.y, v.y, c1);
            c2 = fmaf(w.z, v.z, c2);
            c3 = fmaf(w.w, v.w, c3);
        }
        float acc = (c0 + c1) + (c2 + c3);
        acc += __shfl_xor(acc, 1);
        if (h == 0) h2[n] = sigmoidf_(acc + b2[n]);
    }
    __syncthreads();

    if (tid < 40) {
        int n = tid >> 2, q = tid & 3;
        const float4* wr = (const float4*)(W3 + n * 84);
        const float4* hv = (const float4*)h2;
        float c0 = 0.f, c1 = 0.f, c2 = 0.f, c3 = 0.f;
        for (int k = q; k < 21; k += 4) {
            float4 w = wr[k];
            float4 v = hv[k];
            c0 = fmaf(w.x, v.x, c0);
            c1 = fmaf(w.y, v.y, c1);
            c2 = fmaf(w.z, v.z, c2);
            c3 = fmaf(w.w, v.w, c3);
        }
        float acc = (c0 + c1) + (c2 + c3);
        acc += __shfl_xor(acc, 1);
        acc += __shfl_xor(acc, 2);
        if (q == 0) out[(size_t)b * 10 + n] = sigmoidf_(acc + b3[n]);
    }
}

extern "C" void kernel_launch(void* const* d_in, const int* in_sizes, int n_in,
                              void* d_out, int out_size, void* d_ws, size_t ws_size,
                              hipStream_t stream) {
    const float* x  = (const float*)d_in[0];
    const float* sw = (const float*)d_in[1];
    const float* sa = (const float*)d_in[2];
    const float* W1 = (const float*)d_in[3];
    const float* b1 = (const float*)d_in[4];
    const float* W2 = (const float*)d_in[5];
    const float* b2 = (const float*)d_in[6];
    const float* W3 = (const float*)d_in[7];
    const float* b3 = (const float*)d_in[8];
    float* out = (float*)d_out;

    smorph_net_kernel<<<NB, 256, 0, stream>>>(x, sw, sa, W1, b1, W2, b2, W3, b3, out);
}